// Round 4
// baseline (100.821 us; speedup 1.0000x reference)
//
#include <hip/hip_runtime.h>

#define W_OUT 3840
#define H_OUT 2160
#define IW 1024   // intermediate (cropped) cols
#define IH 576    // intermediate (cropped) rows

__device__ __forceinline__ unsigned int enc_f32(float f) {
    // order-preserving float->uint map (monotone for ALL floats)
    unsigned int b = __float_as_uint(f);
    return b ^ (0x80000000u | (unsigned int)((int)b >> 31));
}

// Kernel 1: sim64[p] = sum_c ref[c]*emb[c][p] / sqrt(sum_c emb[c][p]^2)
// ARITHMETIC VERBATIM FROM ROUND 1 (bitwise-matched the reference).
__global__ __launch_bounds__(256) void sim_kernel(
    const float* __restrict__ emb, const float* __restrict__ ref,
    float* __restrict__ sim)
{
    const int lane = threadIdx.x & 63;
    const int wave = threadIdx.x >> 6;
    const int p = blockIdx.x * 64 + lane;
    const int cbase = wave * 64;
    float dot = 0.f, ss = 0.f;
#pragma unroll 8
    for (int cc = 0; cc < 64; ++cc) {
        int c = cbase + cc;
        float a = emb[c * 4096 + p];
        dot = fmaf(ref[c], a, dot);
        ss  = fmaf(a, a, ss);
    }
    __shared__ float sdot[4][64];
    __shared__ float sss[4][64];
    sdot[wave][lane] = dot;
    sss[wave][lane]  = ss;
    __syncthreads();
    if (wave == 0) {
        float d = (sdot[0][lane] + sdot[1][lane]) + (sdot[2][lane] + sdot[3][lane]);
        float s = (sss[0][lane] + sss[1][lane]) + (sss[2][lane] + sss[3][lane]);
        sim[p] = d / sqrtf(s);
    }
}

// Kernel 2: build the 576x1024 intermediate image ONCE (stage-A math verbatim
// from round 3 -- values bitwise identical to what scan blocks used to build).
// 576 blocks (one per row a) x 256 threads x 4 cols, float4 stores.
__global__ __launch_bounds__(256) void inter_kernel(
    const float* __restrict__ sim, float* __restrict__ I)
{
    const int a   = blockIdx.x;
    const int tid = threadIdx.x;
    const float INV16 = 0.0625f;

    float fa  = ((float)a + 0.5f) * INV16 - 0.5f;
    float faf = floorf(fa);
    float wa  = fa - faf;
    int si = (int)faf;
    int s1 = min(max(si + 1, 0), 63);
    int s0 = min(max(si,     0), 63);
    const float* row0 = sim + s0 * 64;
    const float* row1 = sim + s1 * 64;

    float4 o;
    float* po = &o.x;
#pragma unroll
    for (int k = 0; k < 4; ++k) {
        int b = tid * 4 + k;
        float fb  = ((float)b + 0.5f) * INV16 - 0.5f;
        float fbf = floorf(fb);
        float wb  = fb - fbf;
        int ci = (int)fbf;
        int c1 = min(max(ci + 1, 0), 63);
        int c0 = min(max(ci,     0), 63);
        float v0 = row0[c0] * (1.f - wb) + row0[c1] * wb;
        float v1 = row1[c0] * (1.f - wb) + row1[c1] * wb;
        po[k] = v0 * (1.f - wa) + v1 * wa;
    }
    *(float4*)(I + a * IW + tid * 4) = o;
}

// Kernel 3: one block per output row y. NO LDS, NO BARRIERS, NO ATOMICS.
// Thread t owns 15 contiguous pixels; its 6 taps/row come straight from the
// L2-resident intermediate image. Per-pixel math verbatim from round 3.
__global__ __launch_bounds__(256) void scan_kernel(
    const float* __restrict__ I,
    unsigned long long* __restrict__ cellPart,   // [2160][16] max-keys
    unsigned long long* __restrict__ bgPart)     // [2160][4]  min-keys
{
    const float INV375 = (float)(1.0 / 3.75);   // jax inv_scale, f32
    const int y   = blockIdx.x;
    const int tid = threadIdx.x;

    // second-stage row weights (uniform over block)
    float fy  = ((float)y + 0.5f) * INV375 - 0.5f;
    float fyf = floorf(fy);
    float wy  = fy - fyf;
    int ai = (int)fyf;
    int a1 = min(max(ai + 1, 0), IH - 1);
    int a0 = min(max(ai,     0), IH - 1);
    const float* R0 = I + a0 * IW;
    const float* R1 = I + a1 * IW;

    unsigned long long bestCell = 0ull;                    // max-key
    unsigned long long bestBg   = 0xFFFFFFFFFFFFFFFFull;   // min-key
    const int x0 = tid * 15;
    const unsigned int idxBase = (unsigned int)(y * W_OUT + x0);

#define UPD(F, jj) {                                                        \
        unsigned long long top = ((unsigned long long)enc_f32(F)) << 32;    \
        unsigned int idx = idxBase + (jj);                                  \
        unsigned long long bgk = top | (unsigned long long)idx;             \
        unsigned long long ck  = top | (unsigned long long)(~idx);          \
        if (ck  > bestCell) bestCell = ck;                                  \
        if (bgk < bestBg)   bestBg   = bgk;                                 \
    }

    if (tid == 0 || tid == 255) {
        // boundary threads: clamped per-pixel path (expressions verbatim)
#pragma unroll
        for (int j = 0; j < 15; ++j) {
            int x = x0 + j;
            float fx  = ((float)x + 0.5f) * INV375 - 0.5f;
            float fxf = floorf(fx);
            float wx  = fx - fxf;
            int bi = (int)fxf;
            int b1 = min(max(bi + 1, 0), IW - 1);
            int b0 = min(max(bi,     0), IW - 1);
            float v0 = R0[b0] * (1.f - wx) + R0[b1] * wx;
            float v1 = R1[b0] * (1.f - wx) + R1[b1] * wx;
            float F  = v0 * (1.f - wy) + v1 * wy;
            UPD(F, j)
        }
    } else {
        // interior: pixel j's taps lie in I[4t-1 .. 4t+4] (margins >= 0.033
        // vs f32 index error <= 1.2e-4). 6 floats per row: 1 float4 + 2 scalars.
        const float* b0p = R0 + 4 * tid;
        const float* b1p = R1 + 4 * tid;
        float4 B0 = *(const float4*)b0p;
        float4 B1 = *(const float4*)b1p;
        const float f0[6] = {b0p[-1], B0.x, B0.y, B0.z, B0.w, b0p[4]};
        const float f1[6] = {b1p[-1], B1.x, B1.y, B1.z, B1.w, b1p[4]};

#define PX(j, i0) {                                                         \
            float fx  = ((float)(x0 + (j)) + 0.5f) * INV375 - 0.5f;         \
            float fxf = floorf(fx);                                         \
            float wx  = fx - fxf;                                           \
            float v0 = f0[(i0)] * (1.f - wx) + f0[(i0) + 1] * wx;           \
            float v1 = f1[(i0)] * (1.f - wx) + f1[(i0) + 1] * wx;           \
            float F  = v0 * (1.f - wy) + v1 * wy;                           \
            UPD(F, j)                                                       \
        }
        PX(0,0)  PX(1,0)  PX(2,1)  PX(3,1)  PX(4,1)
        PX(5,1)  PX(6,2)  PX(7,2)  PX(8,2)  PX(9,3)
        PX(10,3) PX(11,3) PX(12,3) PX(13,4) PX(14,4)
#undef PX
    }
#undef UPD

    // per-cell max: 16 threads own one cell -> xor-shuffle within 16 lanes
#pragma unroll
    for (int m = 1; m <= 8; m <<= 1) {
        unsigned long long o = __shfl_xor(bestCell, m, 64);
        if (o > bestCell) bestCell = o;
    }
    if ((tid & 15) == 0) cellPart[y * 16 + (tid >> 4)] = bestCell;

    // bg argmin: per-wave xor-shuffle, one plain store per wave
#pragma unroll
    for (int m = 1; m <= 32; m <<= 1) {
        unsigned long long o = __shfl_xor(bestBg, m, 64);
        if (o < bestBg) bestBg = o;
    }
    if ((tid & 63) == 0) bgPart[y * 4 + (tid >> 6)] = bestBg;
}

// Kernel 4: reduce partials (fully coalesced), threshold at decode,
// stable rank-sort by score desc, write output.
__global__ __launch_bounds__(256) void finalize_kernel(
    const unsigned long long* __restrict__ cellPart,
    const unsigned long long* __restrict__ bgPart,
    float* __restrict__ out)
{
    __shared__ unsigned long long sB[9 * 256];   // [band][rg][cx]
    __shared__ float sk[256];
    __shared__ unsigned long long sb[256];
    const int t = threadIdx.x;

    // phase 1: coalesced scan -- addr = band*3840 + t + 256*j
#pragma unroll
    for (int band = 0; band < 9; ++band) {
        unsigned long long acc = 0ull;
        const unsigned long long* p = cellPart + band * 3840 + t;
#pragma unroll
        for (int j = 0; j < 15; ++j) {
            unsigned long long k = p[j * 256];
            if (k > acc) acc = k;
        }
        sB[band * 256 + t] = acc;
    }

    // bg argmin over 8640 per-wave row minima (coalesced)
    unsigned long long m = 0xFFFFFFFFFFFFFFFFull;
    for (int i = t; i < H_OUT * 4; i += 256) {
        unsigned long long k = bgPart[i];
        if (k < m) m = k;
    }
    sb[t] = m;
    __syncthreads();

    // phase 2: per-cell max over the 16 rg partials
    unsigned long long best = 0ull;
    if (t < 144) {
        int band = t >> 4, cx = t & 15;
#pragma unroll
        for (int k = 0; k < 16; ++k) {
            unsigned long long v = sB[band * 256 + k * 16 + cx];
            if (v > best) best = v;
        }
    }
    float px = -1.f, py = -1.f, ps = -1.f;
    float key = -__builtin_huge_valf();
    if (best != 0ull) {
        unsigned int e = (unsigned int)(best >> 32);
        unsigned int b = (e & 0x80000000u) ? (e ^ 0x80000000u) : ~e;
        float v = __uint_as_float(b);
        if (v > 0.65f) {
            unsigned int idx = ~((unsigned int)(best & 0xFFFFFFFFull));
            px = (float)(idx % W_OUT);
            py = (float)(idx / W_OUT);
            ps = v;
            key = v;
        }
    }

    // bg tree reduce
    for (int s = 128; s > 0; s >>= 1) {
        if (t < s) {
            unsigned long long o = sb[t + s];
            if (o < sb[t]) sb[t] = o;
        }
        __syncthreads();
    }

    // stable rank-sort (desc by score, ties by cell index)
    sk[t] = key;
    __syncthreads();
    int rank = 0;
    for (int j = 0; j < 256; ++j) {
        float kj = sk[j];
        if (kj > key || (kj == key && j < t)) rank++;
    }
    out[rank * 3 + 0] = px;
    out[rank * 3 + 1] = py;
    out[rank * 3 + 2] = ps;
    if (t == 0) {
        unsigned int idx = (unsigned int)(sb[0] & 0xFFFFFFFFull);
        out[256 * 3 + 0] = (float)(idx % W_OUT);  // bg col (x)
        out[256 * 3 + 1] = (float)(idx / W_OUT);  // bg row (y)
    }
}

extern "C" void kernel_launch(void* const* d_in, const int* in_sizes, int n_in,
                              void* d_out, int out_size, void* d_ws, size_t ws_size,
                              hipStream_t stream) {
    (void)in_sizes; (void)n_in; (void)out_size; (void)ws_size;
    const float* emb = (const float*)d_in[0];   // (1,256,64,64) f32
    const float* ref = (const float*)d_in[1];   // (1,256) f32
    // d_in[2] = ori_shape (2160,3840) -- baked as constants per reference trace
    float* out = (float*)d_out;                 // 256*3 points + 2 bg coords

    float* sim = (float*)d_ws;                                                  // 4096 f32   (16 KB)
    float* I   = (float*)((char*)d_ws + 16384);                                 // 576*1024 f32 (2.25 MB)
    unsigned long long* cellPart = (unsigned long long*)((char*)d_ws + 16384 + IH * IW * 4); // 2160*16 u64
    unsigned long long* bgPart   = cellPart + H_OUT * 16;                       // 2160*4 u64

    sim_kernel<<<64, 256, 0, stream>>>(emb, ref, sim);
    inter_kernel<<<IH, 256, 0, stream>>>(sim, I);
    scan_kernel<<<H_OUT, 256, 0, stream>>>(I, cellPart, bgPart);
    finalize_kernel<<<1, 256, 0, stream>>>(cellPart, bgPart, out);
}